// Round 1
// baseline (1789.550 us; speedup 1.0000x reference)
//
#include <hip/hip_runtime.h>
#include <hip/hip_bf16.h>

// ---------------------------------------------------------------------------
// Multimodal LSTM (x3) -> concat -> PTP layer1 (8 windows, rank 16) -> PTP layer2
// Round 0: all-fp32 correctness baseline. No MFMA yet.
// ---------------------------------------------------------------------------

namespace {
constexpr int kB  = 256;
constexpr int kT  = 32;
constexpr int kH  = 256;
constexpr int k4H = 1024;
constexpr int kNW = 8;
constexpr int kR  = 16;
constexpr int kO0 = 128;
constexpr int kO1 = 64;
constexpr int kD1 = 3073;   // 4*768 + 1
constexpr int kD2 = 1025;   // 8*128 + 1
constexpr int k3H = 768;
}

// ---------------- transpose W_hh (4H,H) -> Wt (H,4H) for coalesced streaming
__global__ void k_transpose_whh(const float* __restrict__ w, float* __restrict__ wt) {
    int idx = blockIdx.x * blockDim.x + threadIdx.x;   // 0 .. 4H*H-1
    int n = idx >> 8;          // row in (4H,H), H=256
    int k = idx & 255;
    wt[(size_t)k * k4H + n] = w[idx];
}

// ---------------- GEMM (NT): C[m,n] = sum_k A[m,k]*W[n,k] + b1[n] + b2[n]
// BM=BN=128, BK=16, 256 threads, 8x8 micro-tile. K % 16 == 0.
__global__ __launch_bounds__(256)
void k_gemm_nt_bias(const float* __restrict__ A, const float* __restrict__ W,
                    const float* __restrict__ b1, const float* __restrict__ b2,
                    float* __restrict__ C, int M, int N, int K) {
    __shared__ float As[128][17];
    __shared__ float Bs[128][17];
    const int tid = threadIdx.x;
    const int tx = tid & 15, ty = tid >> 4;
    const int m0 = blockIdx.x * 128, n0 = blockIdx.y * 128;
    const int lrow = tid >> 1, lcol = (tid & 1) * 8;

    float acc[8][8];
#pragma unroll
    for (int i = 0; i < 8; ++i)
#pragma unroll
        for (int j = 0; j < 8; ++j) acc[i][j] = 0.f;

    const float* ap = A + (size_t)(m0 + lrow) * K + lcol;
    const float* wp = W + (size_t)(n0 + lrow) * K + lcol;

    for (int k0 = 0; k0 < K; k0 += 16) {
        float4 a0 = *(const float4*)(ap + k0);
        float4 a1 = *(const float4*)(ap + k0 + 4);
        float4 w0 = *(const float4*)(wp + k0);
        float4 w1 = *(const float4*)(wp + k0 + 4);
        __syncthreads();
        As[lrow][lcol+0] = a0.x; As[lrow][lcol+1] = a0.y;
        As[lrow][lcol+2] = a0.z; As[lrow][lcol+3] = a0.w;
        As[lrow][lcol+4] = a1.x; As[lrow][lcol+5] = a1.y;
        As[lrow][lcol+6] = a1.z; As[lrow][lcol+7] = a1.w;
        Bs[lrow][lcol+0] = w0.x; Bs[lrow][lcol+1] = w0.y;
        Bs[lrow][lcol+2] = w0.z; Bs[lrow][lcol+3] = w0.w;
        Bs[lrow][lcol+4] = w1.x; Bs[lrow][lcol+5] = w1.y;
        Bs[lrow][lcol+6] = w1.z; Bs[lrow][lcol+7] = w1.w;
        __syncthreads();
#pragma unroll
        for (int kk = 0; kk < 16; ++kk) {
            float a[8], b[8];
#pragma unroll
            for (int i = 0; i < 8; ++i) a[i] = As[ty*8+i][kk];
#pragma unroll
            for (int j = 0; j < 8; ++j) b[j] = Bs[tx*8+j][kk];
#pragma unroll
            for (int i = 0; i < 8; ++i)
#pragma unroll
                for (int j = 0; j < 8; ++j) acc[i][j] = fmaf(a[i], b[j], acc[i][j]);
        }
    }
#pragma unroll
    for (int i = 0; i < 8; ++i) {
        const int row = m0 + ty*8 + i;
#pragma unroll
        for (int j = 0; j < 8; ++j) {
            const int col = n0 + tx*8 + j;
            C[(size_t)row * N + col] = acc[i][j] + b1[col] + b2[col];
        }
    }
}

// ---------------- LSTM recurrence: one block = (net, 4 batch rows).
// thread d owns h-dim d (all 4 gates), 4 batch rows; W_hh streamed from L2
// in transposed (H,4H) layout; h shared through LDS.
__global__ __launch_bounds__(256)
void k_lstm(const float* __restrict__ xp_a, const float* __restrict__ xp_v,
            const float* __restrict__ xp_t, const float* __restrict__ wt_base,
            float* __restrict__ hcat) {
    const int net = blockIdx.y;            // 0=audio,1=video,2=text
    const int b0  = blockIdx.x * 4;
    const int d   = threadIdx.x;           // 0..255
    const float* xp = (net == 0) ? xp_a : (net == 1) ? xp_v : xp_t;
    const float* wt = wt_base + (size_t)net * kH * k4H;
    const int coloff = (net == 0) ? 256 : (net == 1) ? 512 : 0;  // cat = [text,audio,video]

    __shared__ float hs[4][kH];
    float c[4] = {0.f, 0.f, 0.f, 0.f};
#pragma unroll
    for (int r = 0; r < 4; ++r) hs[r][d] = 0.f;
    __syncthreads();

    for (int t = 0; t < kT; ++t) {
        float acc0[4] = {0,0,0,0}, acc1[4] = {0,0,0,0};
        float acc2[4] = {0,0,0,0}, acc3[4] = {0,0,0,0};
#pragma unroll 8
        for (int k = 0; k < kH; ++k) {
            const float* wr = wt + (size_t)k * k4H;
            float w0 = wr[d];
            float w1 = wr[256 + d];
            float w2 = wr[512 + d];
            float w3 = wr[768 + d];
#pragma unroll
            for (int r = 0; r < 4; ++r) {
                float hk = hs[r][k];
                acc0[r] = fmaf(hk, w0, acc0[r]);
                acc1[r] = fmaf(hk, w1, acc1[r]);
                acc2[r] = fmaf(hk, w2, acc2[r]);
                acc3[r] = fmaf(hk, w3, acc3[r]);
            }
        }
        float hnew[4];
#pragma unroll
        for (int r = 0; r < 4; ++r) {
            const int row = (b0 + r) * kT + t;
            const float* xr = xp + (size_t)row * k4H;
            float gi = acc0[r] + xr[d];
            float gf = acc1[r] + xr[256 + d];
            float gg = acc2[r] + xr[512 + d];
            float go = acc3[r] + xr[768 + d];
            float ig = 1.f / (1.f + expf(-gi));
            float fg = 1.f / (1.f + expf(-gf));
            float g  = tanhf(gg);
            float og = 1.f / (1.f + expf(-go));
            c[r] = fg * c[r] + ig * g;
            float hv = og * tanhf(c[r]);
            hnew[r] = hv;
            hcat[(size_t)row * k3H + coloff + d] = hv;
        }
        __syncthreads();
#pragma unroll
        for (int r = 0; r < 4; ++r) hs[r][d] = hnew[r];
        __syncthreads();
    }
}

// ---------------- PTP1 GEMM: z1[n,b,r,o] = sum_d x[b,n,d]*F[n,r,d,o]
// x[b,n,0]=0.5, x[b,n,1+j]=hcat_flat[(b*8+n)*3072+j]. BM=128, BN=128(=O0), BK=16.
__global__ __launch_bounds__(256)
void k_ptp1_gemm(const float* __restrict__ hflat, const float* __restrict__ factor,
                 float* __restrict__ z1) {
    const int bt = blockIdx.x;   // 0..1  (batch tile)
    const int r  = blockIdx.y;   // 0..15
    const int n  = blockIdx.z;   // 0..7
    const int tid = threadIdx.x;
    const int tx = tid & 15, ty = tid >> 4;
    const int m0 = bt * 128;
    const int lrow = tid >> 1, lcol = (tid & 1) * 8;   // A tile 128x16
    const int drow = tid >> 4, o0 = (tid & 15) * 8;    // B tile 16x128

    __shared__ float As[128][17];
    __shared__ float Bs[16][128];
    const float* F = factor + (size_t)(n * kR + r) * kD1 * kO0;

    float acc[8][8];
#pragma unroll
    for (int i = 0; i < 8; ++i)
#pragma unroll
        for (int j = 0; j < 8; ++j) acc[i][j] = 0.f;

    for (int k0 = 0; k0 < kD1; k0 += 16) {
        float av[8];
        const int brow = m0 + lrow;
#pragma unroll
        for (int i = 0; i < 8; ++i) {
            int k = k0 + lcol + i;
            av[i] = (k == 0) ? 0.5f
                  : (k < kD1 ? hflat[(size_t)(brow * kNW + n) * 3072 + (k - 1)] : 0.f);
        }
        float bv[8];
        const int dd = k0 + drow;
        if (dd < kD1) {
            const float* fp = F + (size_t)dd * kO0 + o0;
            float4 f0 = *(const float4*)fp;
            float4 f1 = *(const float4*)(fp + 4);
            bv[0]=f0.x; bv[1]=f0.y; bv[2]=f0.z; bv[3]=f0.w;
            bv[4]=f1.x; bv[5]=f1.y; bv[6]=f1.z; bv[7]=f1.w;
        } else {
#pragma unroll
            for (int i = 0; i < 8; ++i) bv[i] = 0.f;
        }
        __syncthreads();
#pragma unroll
        for (int i = 0; i < 8; ++i) As[lrow][lcol + i] = av[i];
#pragma unroll
        for (int i = 0; i < 8; ++i) Bs[drow][o0 + i] = bv[i];
        __syncthreads();
#pragma unroll
        for (int kk = 0; kk < 16; ++kk) {
            float a[8], b[8];
#pragma unroll
            for (int i = 0; i < 8; ++i) a[i] = As[ty*8+i][kk];
#pragma unroll
            for (int j = 0; j < 8; ++j) b[j] = Bs[kk][tx*8+j];
#pragma unroll
            for (int i = 0; i < 8; ++i)
#pragma unroll
                for (int j = 0; j < 8; ++j) acc[i][j] = fmaf(a[i], b[j], acc[i][j]);
        }
    }
#pragma unroll
    for (int i = 0; i < 8; ++i) {
        const int b = m0 + ty*8 + i;
        const size_t base = ((size_t)(n * kB + b) * kR + r) * kO0;
#pragma unroll
        for (int j = 0; j < 8; ++j) z1[base + tx*8 + j] = acc[i][j];
    }
}

// ---------------- PTP1 epilogue: p=z^3, sign-sqrt, L2-normalize over o,
// f1[b,n,o] = bias[n,o] + sum_r w[n,r]*p/||p||
__global__ __launch_bounds__(128)
void k_ptp1_post(const float* __restrict__ z1, const float* __restrict__ w,
                 const float* __restrict__ bias, float* __restrict__ f1) {
    const int b = blockIdx.x;   // 0..255
    const int n = blockIdx.y;   // 0..7
    const int o = threadIdx.x;  // 0..127
    __shared__ float part[2];
    float sv[kR], nrm[kR];
    const size_t zbase = (size_t)(n * kB + b) * kR * kO0;
#pragma unroll
    for (int r = 0; r < kR; ++r) {
        float v = z1[zbase + r * kO0 + o];
        float a = fabsf(v);
        float s = copysignf(a * sqrtf(a), v);   // sign(z)*|z|^1.5
        sv[r] = s;
        float t = s * s;                         // |z|^3
#pragma unroll
        for (int off = 1; off < 64; off <<= 1) t += __shfl_xor(t, off, 64);
        if ((threadIdx.x & 63) == 0) part[threadIdx.x >> 6] = t;
        __syncthreads();
        nrm[r] = sqrtf(part[0] + part[1]);
        __syncthreads();
    }
    float out = bias[n * kO0 + o];
#pragma unroll
    for (int r = 0; r < kR; ++r) out += w[n * kR + r] * sv[r] / nrm[r];
    f1[((size_t)b * kNW + n) * kO0 + o] = out;
}

// ---------------- PTP2 GEMM: z2[b,r,o] = sum_d x2[b,d]*F2[r,d,o]
// x2[b,0]=0.5, x2[b,1+j]=f1_flat[b*1024+j]. block=(32 rows, r); 256 threads.
__global__ __launch_bounds__(256)
void k_ptp2_gemm(const float* __restrict__ f1flat, const float* __restrict__ factor2,
                 float* __restrict__ z2) {
    const int b0 = blockIdx.x * 32;
    const int r  = blockIdx.y;
    const int tx = threadIdx.x & 63;   // o
    const int ty = threadIdx.x >> 6;   // 0..3 (row group)
    __shared__ float xs[32][128];
    float acc[8];
#pragma unroll
    for (int i = 0; i < 8; ++i) acc[i] = 0.f;
    const float* F = factor2 + (size_t)r * kD2 * kO1;

    for (int k0 = 0; k0 < kD2; k0 += 128) {
        const int len = min(128, kD2 - k0);
        {
            const int row = threadIdx.x >> 3;        // 0..31
            const int c0  = (threadIdx.x & 7) * 16;  // 0..112
#pragma unroll
            for (int i = 0; i < 16; ++i) {
                int k = k0 + c0 + i;
                float v = (k == 0) ? 0.5f
                        : (k < kD2 ? f1flat[(size_t)(b0 + row) * 1024 + (k - 1)] : 0.f);
                xs[row][c0 + i] = v;
            }
        }
        __syncthreads();
        for (int dd = 0; dd < len; ++dd) {
            float wv = F[(size_t)(k0 + dd) * kO1 + tx];
#pragma unroll
            for (int i = 0; i < 8; ++i) acc[i] = fmaf(xs[ty*8+i][dd], wv, acc[i]);
        }
        __syncthreads();
    }
#pragma unroll
    for (int i = 0; i < 8; ++i) {
        const int b = b0 + ty*8 + i;
        z2[((size_t)b * kR + r) * kO1 + tx] = acc[i];
    }
}

// ---------------- PTP2 epilogue -> final output (B,64) fp32
__global__ __launch_bounds__(64)
void k_ptp2_post(const float* __restrict__ z2, const float* __restrict__ w2,
                 const float* __restrict__ b2, float* __restrict__ out) {
    const int b = blockIdx.x;
    const int o = threadIdx.x;  // 0..63
    float sv[kR], nrm[kR];
#pragma unroll
    for (int r = 0; r < kR; ++r) {
        float v = z2[((size_t)b * kR + r) * kO1 + o];
        float a = fabsf(v);
        float s = copysignf(a * sqrtf(a), v);
        sv[r] = s;
        float t = s * s;
#pragma unroll
        for (int off = 1; off < 64; off <<= 1) t += __shfl_xor(t, off, 64);
        nrm[r] = sqrtf(t);
    }
    float acc = b2[o];
#pragma unroll
    for (int r = 0; r < kR; ++r) acc += w2[r] * sv[r] / nrm[r];
    out[(size_t)b * kO1 + o] = acc;
}

// ---------------------------------------------------------------------------
extern "C" void kernel_launch(void* const* d_in, const int* in_sizes, int n_in,
                              void* d_out, int out_size, void* d_ws, size_t ws_size,
                              hipStream_t stream) {
    const float* audio_x  = (const float*)d_in[0];
    const float* video_x  = (const float*)d_in[1];
    const float* text_x   = (const float*)d_in[2];
    const float* aw_ih    = (const float*)d_in[3];
    const float* aw_hh    = (const float*)d_in[4];
    const float* ab_ih    = (const float*)d_in[5];
    const float* ab_hh    = (const float*)d_in[6];
    const float* vw_ih    = (const float*)d_in[7];
    const float* vw_hh    = (const float*)d_in[8];
    const float* vb_ih    = (const float*)d_in[9];
    const float* vb_hh    = (const float*)d_in[10];
    const float* txw_ih   = (const float*)d_in[11];
    const float* txw_hh   = (const float*)d_in[12];
    const float* txb_ih   = (const float*)d_in[13];
    const float* txb_hh   = (const float*)d_in[14];
    const float* l1_factor = (const float*)d_in[15];
    const float* l1_weight = (const float*)d_in[16];
    const float* l1_bias   = (const float*)d_in[17];
    const float* l2_factor = (const float*)d_in[18];
    const float* l2_weight = (const float*)d_in[19];
    const float* l2_bias   = (const float*)d_in[20];

    float* ws = (float*)d_ws;
    // workspace layout (floats); total 32,243,712 floats = 129 MB
    float* xp_a = ws;                    //  8,388,608  (B*T, 4H)
    float* xp_v = ws + 8388608;          //  8,388,608
    float* xp_t = ws + 16777216;         //  8,388,608
    float* hcat = ws + 25165824;         //  6,291,456  (B*T, 3H) = [text|audio|video]
    float* wt   = ws + 31457280;         //    786,432  (3 nets transposed W_hh)
    // aliases for the post-LSTM phase (xp buffers are dead by then)
    float* z1 = xp_a;                    //  4,194,304  (n,b,r,o)
    float* f1 = xp_v;                    //    262,144  (b,n,o)
    float* z2 = xp_v + 262144;           //    262,144  (b,r,o)

    // 1) transpose recurrent weights
    k_transpose_whh<<<1024, 256, 0, stream>>>(aw_hh,  wt);
    k_transpose_whh<<<1024, 256, 0, stream>>>(vw_hh,  wt + 262144);
    k_transpose_whh<<<1024, 256, 0, stream>>>(txw_hh, wt + 524288);

    // 2) input projections xp = x @ W_ih^T + b_ih + b_hh
    dim3 gp(8192 / 128, 1024 / 128);
    k_gemm_nt_bias<<<gp, 256, 0, stream>>>(audio_x, aw_ih,  ab_ih,  ab_hh,  xp_a, 8192, 1024, 128);
    k_gemm_nt_bias<<<gp, 256, 0, stream>>>(video_x, vw_ih,  vb_ih,  vb_hh,  xp_v, 8192, 1024, 256);
    k_gemm_nt_bias<<<gp, 256, 0, stream>>>(text_x,  txw_ih, txb_ih, txb_hh, xp_t, 8192, 1024, 768);

    // 3) LSTM recurrences (all 3 nets concurrent), writes concat layout
    k_lstm<<<dim3(64, 3), 256, 0, stream>>>(xp_a, xp_v, xp_t, wt, hcat);

    // 4) PTP layer 1
    k_ptp1_gemm<<<dim3(2, 16, 8), 256, 0, stream>>>(hcat, l1_factor, z1);
    k_ptp1_post<<<dim3(256, 8), 128, 0, stream>>>(z1, l1_weight, l1_bias, f1);

    // 5) PTP layer 2 -> output
    k_ptp2_gemm<<<dim3(8, 16), 256, 0, stream>>>(f1, l2_factor, z2);
    k_ptp2_post<<<256, 64, 0, stream>>>(z2, l2_weight, l2_bias, (float*)d_out);
}

// Round 2
// 685.997 us; speedup vs baseline: 2.6087x; 2.6087x over previous
//
#include <hip/hip_runtime.h>
#include <hip/hip_bf16.h>

// ---------------------------------------------------------------------------
// Multimodal LSTM (x3) -> concat -> PTP layer1 (8 windows, rank 16) -> PTP layer2
// Round 2: bf16 MFMA for projections + PTP1; restructured LSTM recurrence
// (1024-thr blocks, 4-way k-split, bf16 weights) to fix latency-bound k_lstm.
// ---------------------------------------------------------------------------

namespace {
constexpr int kB  = 256;
constexpr int kT  = 32;
constexpr int kH  = 256;
constexpr int k4H = 1024;
constexpr int kNW = 8;
constexpr int kR  = 16;
constexpr int kO0 = 128;
constexpr int kO1 = 64;
constexpr int kD1 = 3073;   // 4*768 + 1
constexpr int kD2 = 1025;   // 8*128 + 1
constexpr int k3H = 768;
}

typedef __attribute__((ext_vector_type(8))) short short8;   // 8 bf16 (4 VGPRs)
typedef __attribute__((ext_vector_type(4))) float f32x4;    // MFMA acc
typedef __attribute__((ext_vector_type(4))) unsigned int u32x4;

__device__ __forceinline__ unsigned int pack2bf(float a, float b) {
    // two fp32 -> packed bf16 pair (truncation; uniform bias cancels in p/||p||)
    unsigned int ua = __builtin_bit_cast(unsigned int, a);
    unsigned int ub = __builtin_bit_cast(unsigned int, b);
    return (ua >> 16) | (ub & 0xffff0000u);
}
__device__ __forceinline__ float bflo(unsigned int u) {
    return __builtin_bit_cast(float, u << 16);
}
__device__ __forceinline__ float bfhi(unsigned int u) {
    return __builtin_bit_cast(float, u & 0xffff0000u);
}

// ---------------- W_hh (4H,H) fp32 -> bf16 packed [k=256][d=256][gate=4]
// (uint2 per (k,d): .x = i|f, .y = g|o). Coalesced reads along k.
__global__ void k_prep_whh(const float* __restrict__ wa, const float* __restrict__ wv,
                           const float* __restrict__ wtx, uint2* __restrict__ wt) {
    int idx = blockIdx.x * 256 + threadIdx.x;   // 0 .. 3*65536-1
    int net = idx >> 16;
    int rem = idx & 65535;
    int dd  = rem >> 8;
    int k   = rem & 255;
    const float* w = (net == 0) ? wa : (net == 1) ? wv : wtx;
    float wi = w[(0 * 256 + dd) * 256 + k];
    float wf = w[(1 * 256 + dd) * 256 + k];
    float wg = w[(2 * 256 + dd) * 256 + k];
    float wo = w[(3 * 256 + dd) * 256 + k];
    wt[(size_t)net * 65536 + (size_t)k * 256 + dd] = make_uint2(pack2bf(wi, wf), pack2bf(wg, wo));
}

// ---------------- MFMA GEMM (NT) for input projections:
// C[m,n] = sum_k A[m,k]*W[n,k] + b1[n] + b2[n].  M=8192, N=1024, K in {128,256,768}.
// BM=256, BN=128, BK=32, 512 threads (8 waves, 4m x 2n), fp32->bf16 staged in-kernel.
__global__ __launch_bounds__(512)
void k_mm_proj(const float* __restrict__ A, const float* __restrict__ W,
               const float* __restrict__ b1, const float* __restrict__ b2,
               float* __restrict__ C, int K) {
    __shared__ __align__(16) unsigned int As[256 * 20];   // [row][20 uints = 40 bf16], pitch 80B
    __shared__ __align__(16) unsigned int Bs[128 * 20];
    const int tid  = threadIdx.x;
    const int lane = tid & 63;
    const int wid  = tid >> 6;
    const int wm   = wid >> 1, wn = wid & 1;
    const int m0 = blockIdx.x * 256, n0 = blockIdx.y * 128;
    const int nstep = K >> 5;

    const int ar = tid >> 1, akq = (tid & 1) * 16;   // A-stage: row, k-offset (16 floats)
    const int br = tid >> 2, bkq = (tid & 3) * 8;    // B-stage: row, k-offset (8 floats)
    const float* ap = A + (size_t)(m0 + ar) * K + akq;
    const float* wp = W + (size_t)(n0 + br) * K + bkq;

    float4 aR[4], bR[2];
    auto loadA = [&](int s) {
#pragma unroll
        for (int i = 0; i < 4; ++i) aR[i] = *(const float4*)(ap + s * 32 + i * 4);
    };
    auto loadB = [&](int s) {
#pragma unroll
        for (int i = 0; i < 2; ++i) bR[i] = *(const float4*)(wp + s * 32 + i * 4);
    };

    f32x4 acc[4][4];
#pragma unroll
    for (int i = 0; i < 4; ++i)
#pragma unroll
        for (int j = 0; j < 4; ++j) acc[i][j] = (f32x4){0.f, 0.f, 0.f, 0.f};

    loadA(0); loadB(0);
    for (int s = 0; s < nstep; ++s) {
        __syncthreads();
        {
            u32x4 w0 = { pack2bf(aR[0].x, aR[0].y), pack2bf(aR[0].z, aR[0].w),
                         pack2bf(aR[1].x, aR[1].y), pack2bf(aR[1].z, aR[1].w) };
            u32x4 w1 = { pack2bf(aR[2].x, aR[2].y), pack2bf(aR[2].z, aR[2].w),
                         pack2bf(aR[3].x, aR[3].y), pack2bf(aR[3].z, aR[3].w) };
            *(u32x4*)&As[ar * 20 + (akq >> 1)]     = w0;
            *(u32x4*)&As[ar * 20 + (akq >> 1) + 4] = w1;
            u32x4 v0 = { pack2bf(bR[0].x, bR[0].y), pack2bf(bR[0].z, bR[0].w),
                         pack2bf(bR[1].x, bR[1].y), pack2bf(bR[1].z, bR[1].w) };
            *(u32x4*)&Bs[br * 20 + (bkq >> 1)] = v0;
        }
        __syncthreads();
        if (s + 1 < nstep) { loadA(s + 1); loadB(s + 1); }
        short8 af[4], bf[4];
#pragma unroll
        for (int i = 0; i < 4; ++i)
            af[i] = __builtin_bit_cast(short8,
                *(const u32x4*)&As[(wm * 64 + i * 16 + (lane & 15)) * 20 + (lane >> 4) * 4]);
#pragma unroll
        for (int j = 0; j < 4; ++j)
            bf[j] = __builtin_bit_cast(short8,
                *(const u32x4*)&Bs[(wn * 64 + j * 16 + (lane & 15)) * 20 + (lane >> 4) * 4]);
#pragma unroll
        for (int i = 0; i < 4; ++i)
#pragma unroll
            for (int j = 0; j < 4; ++j)
                acc[i][j] = __builtin_amdgcn_mfma_f32_16x16x32_bf16(af[i], bf[j], acc[i][j], 0, 0, 0);
    }
#pragma unroll
    for (int i = 0; i < 4; ++i) {
#pragma unroll
        for (int j = 0; j < 4; ++j) {
            const int col = n0 + wn * 64 + j * 16 + (lane & 15);
            const float badd = b1[col] + b2[col];
#pragma unroll
            for (int e = 0; e < 4; ++e) {
                const int row = m0 + wm * 64 + i * 16 + (lane >> 4) * 4 + e;
                C[(size_t)row * 1024 + col] = acc[i][j][e] + badd;
            }
        }
    }
}

// ---------------- LSTM recurrence, restructured:
// 1024 threads = 4 k-groups x 256 h-dims; 4 batch rows/block; bf16 W streamed
// from L2; partial gate sums reduced through LDS; fp32 state.
__global__ __launch_bounds__(1024)
void k_lstm2(const float* __restrict__ xp_a, const float* __restrict__ xp_v,
             const float* __restrict__ xp_t, const uint2* __restrict__ wt_all,
             float* __restrict__ hcat) {
    const int net = blockIdx.y;            // 0=audio,1=video,2=text
    const int b0  = blockIdx.x * 4;
    const int tid = threadIdx.x;
    const int d   = tid & 255;
    const int kg  = tid >> 8;              // 0..3
    const float* xp = (net == 0) ? xp_a : (net == 1) ? xp_v : xp_t;
    const uint2* wt = wt_all + (size_t)net * 65536;
    const int coloff = (net == 0) ? 256 : (net == 1) ? 512 : 0;  // cat=[text,audio,video]

    __shared__ float hs[256][4];           // [h-dim][batch row]
    __shared__ float red[3][256][20];      // partial sums, pitch 20 for alignment
    float c[4] = {0.f, 0.f, 0.f, 0.f};
    if (kg == 0) { hs[d][0] = 0.f; hs[d][1] = 0.f; hs[d][2] = 0.f; hs[d][3] = 0.f; }
    __syncthreads();

    for (int t = 0; t < kT; ++t) {
        float a0[4] = {0,0,0,0}, a1[4] = {0,0,0,0}, a2[4] = {0,0,0,0}, a3[4] = {0,0,0,0};
        const uint2* wp = wt + (size_t)(kg * 64) * 256 + d;
#pragma unroll 4
        for (int k = 0; k < 64; ++k) {
            uint2 w = wp[(size_t)k * 256];
            float wi = bflo(w.x), wf = bfhi(w.x), wg = bflo(w.y), wo = bfhi(w.y);
            float4 h4 = *(const float4*)&hs[kg * 64 + k][0];
            float hk[4] = {h4.x, h4.y, h4.z, h4.w};
#pragma unroll
            for (int r = 0; r < 4; ++r) {
                a0[r] = fmaf(hk[r], wi, a0[r]);
                a1[r] = fmaf(hk[r], wf, a1[r]);
                a2[r] = fmaf(hk[r], wg, a2[r]);
                a3[r] = fmaf(hk[r], wo, a3[r]);
            }
        }
        if (kg > 0) {
            float* rp = &red[kg - 1][d][0];
            *(float4*)(rp)      = make_float4(a0[0], a0[1], a0[2], a0[3]);
            *(float4*)(rp + 4)  = make_float4(a1[0], a1[1], a1[2], a1[3]);
            *(float4*)(rp + 8)  = make_float4(a2[0], a2[1], a2[2], a2[3]);
            *(float4*)(rp + 12) = make_float4(a3[0], a3[1], a3[2], a3[3]);
        }
        __syncthreads();
        if (kg == 0) {
#pragma unroll
            for (int r = 0; r < 4; ++r) {
                const int row = (b0 + r) * kT + t;
                const float* xr = xp + (size_t)row * k4H;
                float gi = a0[r] + red[0][d][r]      + red[1][d][r]      + red[2][d][r]      + xr[d];
                float gf = a1[r] + red[0][d][4 + r]  + red[1][d][4 + r]  + red[2][d][4 + r]  + xr[256 + d];
                float gg = a2[r] + red[0][d][8 + r]  + red[1][d][8 + r]  + red[2][d][8 + r]  + xr[512 + d];
                float go = a3[r] + red[0][d][12 + r] + red[1][d][12 + r] + red[2][d][12 + r] + xr[768 + d];
                float ig = 1.f / (1.f + expf(-gi));
                float fg = 1.f / (1.f + expf(-gf));
                float g  = tanhf(gg);
                float og = 1.f / (1.f + expf(-go));
                c[r] = fg * c[r] + ig * g;
                float hv = og * tanhf(c[r]);
                hs[d][r] = hv;
                hcat[(size_t)row * k3H + coloff + d] = hv;
            }
        }
        __syncthreads();
    }
}

// ---------------- PTP1 MFMA GEMM: z1p[ks][n][b][r][o] = sum_{d in ks-half} x*F
// x[b,n,1+j] = hflat[(b*8+n)*3072 + j]; const (d=0) term added in post.
// BM=256 (all b), BN=128 (all o), BK=32; K-split 2 x 1536; 48 K-steps.
__global__ __launch_bounds__(512)
void k_ptp1_mfma(const float* __restrict__ hflat, const float* __restrict__ factor,
                 float* __restrict__ z1p) {
    __shared__ __align__(16) unsigned int As[256 * 20];
    __shared__ __align__(16) unsigned short Bs[128 * 40];   // [o][k], pitch 40 (80B)
    const int tid  = threadIdx.x;
    const int lane = tid & 63;
    const int wid  = tid >> 6;
    const int wm   = wid >> 1, wn = wid & 1;
    const int r  = blockIdx.x >> 1;
    const int ks = blockIdx.x & 1;
    const int n  = blockIdx.y;
    const int d0 = ks * 1536;

    const int ar = tid >> 1, akq = (tid & 1) * 16;
    const int bk = tid >> 4, boq = (tid & 15) * 8;
    const float* ap = hflat + (size_t)(ar * kNW + n) * 3072 + d0 + akq;
    const float* fp = factor + ((size_t)(n * kR + r) * kD1 + 1 + d0 + bk) * kO0 + boq;

    float4 aR[4], bR[2];
    auto loadA = [&](int s) {
#pragma unroll
        for (int i = 0; i < 4; ++i) aR[i] = *(const float4*)(ap + s * 32 + i * 4);
    };
    auto loadB = [&](int s) {
        bR[0] = *(const float4*)(fp + (size_t)s * 32 * kO0);
        bR[1] = *(const float4*)(fp + (size_t)s * 32 * kO0 + 4);
    };

    f32x4 acc[4][4];
#pragma unroll
    for (int i = 0; i < 4; ++i)
#pragma unroll
        for (int j = 0; j < 4; ++j) acc[i][j] = (f32x4){0.f, 0.f, 0.f, 0.f};

    loadA(0); loadB(0);
    for (int s = 0; s < 48; ++s) {
        __syncthreads();
        {
            u32x4 w0 = { pack2bf(aR[0].x, aR[0].y), pack2bf(aR[0].z, aR[0].w),
                         pack2bf(aR[1].x, aR[1].y), pack2bf(aR[1].z, aR[1].w) };
            u32x4 w1 = { pack2bf(aR[2].x, aR[2].y), pack2bf(aR[2].z, aR[2].w),
                         pack2bf(aR[3].x, aR[3].y), pack2bf(aR[3].z, aR[3].w) };
            *(u32x4*)&As[ar * 20 + (akq >> 1)]     = w0;
            *(u32x4*)&As[ar * 20 + (akq >> 1) + 4] = w1;
            // B transposed stage: Bs[o][k] = bf16(F[d][o])
            float bv[8] = {bR[0].x, bR[0].y, bR[0].z, bR[0].w,
                           bR[1].x, bR[1].y, bR[1].z, bR[1].w};
#pragma unroll
            for (int i = 0; i < 8; ++i)
                Bs[(boq + i) * 40 + bk] =
                    (unsigned short)(__builtin_bit_cast(unsigned int, bv[i]) >> 16);
        }
        __syncthreads();
        if (s + 1 < 48) { loadA(s + 1); loadB(s + 1); }
        short8 af[4], bf[4];
#pragma unroll
        for (int i = 0; i < 4; ++i)
            af[i] = __builtin_bit_cast(short8,
                *(const u32x4*)&As[(wm * 64 + i * 16 + (lane & 15)) * 20 + (lane >> 4) * 4]);
#pragma unroll
        for (int j = 0; j < 4; ++j)
            bf[j] = __builtin_bit_cast(short8,
                *(const u32x4*)&Bs[(wn * 64 + j * 16 + (lane & 15)) * 40 + (lane >> 4) * 8]);
#pragma unroll
        for (int i = 0; i < 4; ++i)
#pragma unroll
            for (int j = 0; j < 4; ++j)
                acc[i][j] = __builtin_amdgcn_mfma_f32_16x16x32_bf16(af[i], bf[j], acc[i][j], 0, 0, 0);
    }
    const size_t zb = ((size_t)ks * 8 + n) * 256;
#pragma unroll
    for (int i = 0; i < 4; ++i) {
#pragma unroll
        for (int j = 0; j < 4; ++j) {
            const int col = wn * 64 + j * 16 + (lane & 15);
#pragma unroll
            for (int e = 0; e < 4; ++e) {
                const int row = wm * 64 + i * 16 + (lane >> 4) * 4 + e;
                z1p[((zb + row) * kR + r) * kO0 + col] = acc[i][j][e];
            }
        }
    }
}

// ---------------- PTP1 epilogue: z = part0+part1 + 0.5*F[n,r,0,o]; p=z^3,
// sign-sqrt, L2-normalize over o, f1[b,n,o] = bias + sum_r w*p_hat
__global__ __launch_bounds__(128)
void k_ptp1_post(const float* __restrict__ z1p, const float* __restrict__ factor,
                 const float* __restrict__ w, const float* __restrict__ bias,
                 float* __restrict__ f1) {
    const int b = blockIdx.x;   // 0..255
    const int n = blockIdx.y;   // 0..7
    const int o = threadIdx.x;  // 0..127
    __shared__ float part[2];
    float sv[kR], nrm[kR];
    const size_t zbase = ((size_t)n * kB + b) * kR * kO0;
    constexpr size_t kHalf = (size_t)8 * 256 * kR * kO0;   // 4,194,304
#pragma unroll
    for (int r = 0; r < kR; ++r) {
        float v = z1p[zbase + r * kO0 + o] + z1p[kHalf + zbase + r * kO0 + o]
                + 0.5f * factor[(size_t)(n * kR + r) * kD1 * kO0 + o];
        float a = fabsf(v);
        float s = copysignf(a * sqrtf(a), v);   // sign(z)*|z|^1.5
        sv[r] = s;
        float t = s * s;                         // |z|^3
#pragma unroll
        for (int off = 1; off < 64; off <<= 1) t += __shfl_xor(t, off, 64);
        if ((threadIdx.x & 63) == 0) part[threadIdx.x >> 6] = t;
        __syncthreads();
        nrm[r] = sqrtf(part[0] + part[1]);
        __syncthreads();
    }
    float out = bias[n * kO0 + o];
#pragma unroll
    for (int r = 0; r < kR; ++r) out += w[n * kR + r] * sv[r] / nrm[r];
    f1[((size_t)b * kNW + n) * kO0 + o] = out;
}

// ---------------- PTP2 GEMM: z2[b,r,o] = sum_d x2[b,d]*F2[r,d,o]
__global__ __launch_bounds__(256)
void k_ptp2_gemm(const float* __restrict__ f1flat, const float* __restrict__ factor2,
                 float* __restrict__ z2) {
    const int b0 = blockIdx.x * 32;
    const int r  = blockIdx.y;
    const int tx = threadIdx.x & 63;   // o
    const int ty = threadIdx.x >> 6;   // 0..3
    __shared__ float xs[32][128];
    float acc[8];
#pragma unroll
    for (int i = 0; i < 8; ++i) acc[i] = 0.f;
    const float* F = factor2 + (size_t)r * kD2 * kO1;

    for (int k0 = 0; k0 < kD2; k0 += 128) {
        const int len = min(128, kD2 - k0);
        {
            const int row = threadIdx.x >> 3;
            const int c0  = (threadIdx.x & 7) * 16;
#pragma unroll
            for (int i = 0; i < 16; ++i) {
                int k = k0 + c0 + i;
                float v = (k == 0) ? 0.5f
                        : (k < kD2 ? f1flat[(size_t)(b0 + row) * 1024 + (k - 1)] : 0.f);
                xs[row][c0 + i] = v;
            }
        }
        __syncthreads();
        for (int dd = 0; dd < len; ++dd) {
            float wv = F[(size_t)(k0 + dd) * kO1 + tx];
#pragma unroll
            for (int i = 0; i < 8; ++i) acc[i] = fmaf(xs[ty * 8 + i][dd], wv, acc[i]);
        }
        __syncthreads();
    }
#pragma unroll
    for (int i = 0; i < 8; ++i) {
        const int b = b0 + ty * 8 + i;
        z2[((size_t)b * kR + r) * kO1 + tx] = acc[i];
    }
}

// ---------------- PTP2 epilogue -> final output (B,64) fp32
__global__ __launch_bounds__(64)
void k_ptp2_post(const float* __restrict__ z2, const float* __restrict__ w2,
                 const float* __restrict__ b2, float* __restrict__ out) {
    const int b = blockIdx.x;
    const int o = threadIdx.x;
    float sv[kR], nrm[kR];
#pragma unroll
    for (int r = 0; r < kR; ++r) {
        float v = z2[((size_t)b * kR + r) * kO1 + o];
        float a = fabsf(v);
        float s = copysignf(a * sqrtf(a), v);
        sv[r] = s;
        float t = s * s;
#pragma unroll
        for (int off = 1; off < 64; off <<= 1) t += __shfl_xor(t, off, 64);
        nrm[r] = sqrtf(t);
    }
    float acc = b2[o];
#pragma unroll
    for (int r = 0; r < kR; ++r) acc += w2[r] * sv[r] / nrm[r];
    out[(size_t)b * kO1 + o] = acc;
}

// ---------------------------------------------------------------------------
extern "C" void kernel_launch(void* const* d_in, const int* in_sizes, int n_in,
                              void* d_out, int out_size, void* d_ws, size_t ws_size,
                              hipStream_t stream) {
    const float* audio_x  = (const float*)d_in[0];
    const float* video_x  = (const float*)d_in[1];
    const float* text_x   = (const float*)d_in[2];
    const float* aw_ih    = (const float*)d_in[3];
    const float* aw_hh    = (const float*)d_in[4];
    const float* ab_ih    = (const float*)d_in[5];
    const float* ab_hh    = (const float*)d_in[6];
    const float* vw_ih    = (const float*)d_in[7];
    const float* vw_hh    = (const float*)d_in[8];
    const float* vb_ih    = (const float*)d_in[9];
    const float* vb_hh    = (const float*)d_in[10];
    const float* txw_ih   = (const float*)d_in[11];
    const float* txw_hh   = (const float*)d_in[12];
    const float* txb_ih   = (const float*)d_in[13];
    const float* txb_hh   = (const float*)d_in[14];
    const float* l1_factor = (const float*)d_in[15];
    const float* l1_weight = (const float*)d_in[16];
    const float* l1_bias   = (const float*)d_in[17];
    const float* l2_factor = (const float*)d_in[18];
    const float* l2_weight = (const float*)d_in[19];
    const float* l2_bias   = (const float*)d_in[20];

    float* ws = (float*)d_ws;
    // workspace layout (floats); total 32,243,712 floats = 129 MB
    float* xp_a = ws;                    //  8,388,608  (B*T, 4H)
    float* xp_v = ws + 8388608;          //  8,388,608
    float* xp_t = ws + 16777216;         //  8,388,608
    float* hcat = ws + 25165824;         //  6,291,456  (B*T, 3H) = [text|audio|video]
    uint2* wt   = (uint2*)(ws + 31457280); //  393,216 uint2 (3 nets bf16-packed W_hh)
    // aliases for the post-LSTM phase (xp buffers are dead by then)
    float* z1p = xp_a;                   //  8,388,608  (2 k-split partials)
    float* f1  = xp_v;                   //    262,144  (b,n,o)
    float* z2  = xp_v + 262144;          //    262,144  (b,r,o)

    // 1) pack recurrent weights to bf16 [k][d][gate]
    k_prep_whh<<<768, 256, 0, stream>>>(aw_hh, vw_hh, txw_hh, wt);

    // 2) input projections xp = x @ W_ih^T + b_ih + b_hh  (bf16 MFMA)
    dim3 gp(32, 8);
    k_mm_proj<<<gp, 512, 0, stream>>>(audio_x, aw_ih,  ab_ih,  ab_hh,  xp_a, 128);
    k_mm_proj<<<gp, 512, 0, stream>>>(video_x, vw_ih,  vb_ih,  vb_hh,  xp_v, 256);
    k_mm_proj<<<gp, 512, 0, stream>>>(text_x,  txw_ih, txb_ih, txb_hh, xp_t, 768);

    // 3) LSTM recurrences (all 3 nets concurrent), writes concat layout
    k_lstm2<<<dim3(64, 3), 1024, 0, stream>>>(xp_a, xp_v, xp_t, wt, hcat);

    // 4) PTP layer 1 (bf16 MFMA, K-split 2; const term in post)
    k_ptp1_mfma<<<dim3(32, 8), 512, 0, stream>>>(hcat, l1_factor, z1p);
    k_ptp1_post<<<dim3(256, 8), 128, 0, stream>>>(z1p, l1_factor, l1_weight, l1_bias, f1);

    // 5) PTP layer 2 -> output
    k_ptp2_gemm<<<dim3(8, 16), 256, 0, stream>>>(f1, l2_factor, z2);
    k_ptp2_post<<<256, 64, 0, stream>>>(z2, l2_weight, l2_bias, (float*)d_out);
}